// Round 14
// baseline (5250.093 us; speedup 1.0000x reference)
//
#include <hip/hip_runtime.h>
#include <hip/hip_fp16.h>

typedef float f32x4 __attribute__((ext_vector_type(4)));
typedef _Float16 half8 __attribute__((ext_vector_type(8)));
typedef _Float16 h2_t __attribute__((ext_vector_type(2)));

#define EMB   300
#define HID   300
#define G4    1200
#define TAGS  64
#define BB    64
#define TT    512
#define MM    (BB*TT)
#define KQ    38        // uint4 (8 fp16) k-chunks: 304 k (300 + 4 pad)
#define NC    6         // k-chunks of U cached in LDS
#define PR    16        // k-chunks of U persistent in registers (128 regs)
#define NST   (KQ - NC - PR)   // 16 streamed chunks
#define NTH   704
#define WCOLS 1216      // padded col count of Wht
#define WK    320       // padded k of Wht
// k2 dynamic LDS: Us | W2s | h32 | h16
#define SMEM2 (NC*1200*16 + 300*64*2 + 2*304*4 + 2*304*2)

__device__ __forceinline__ float sigm(float x) {
    return 1.0f / (1.0f + __expf(-x));
}
__device__ __forceinline__ float tanh_fast(float x) {
    float e = __expf(-2.0f * fabsf(x));
    float r = (1.0f - e) / (1.0f + e);
    return copysignf(r, x);
}
__device__ __forceinline__ float fdot2f(unsigned u, unsigned h, float acc) {
#if __has_builtin(__builtin_amdgcn_fdot2)
    return __builtin_amdgcn_fdot2(__builtin_bit_cast(h2_t, u),
                                  __builtin_bit_cast(h2_t, h), acc, false);
#else
    h2_t a = __builtin_bit_cast(h2_t, u), b = __builtin_bit_cast(h2_t, h);
    acc = fmaf((float)a.x, (float)b.x, acc);
    return fmaf((float)a.y, (float)b.y, acc);
#endif
}
__device__ __forceinline__ unsigned short f2h_bits(float f) {
    _Float16 h = (_Float16)f;
    return __builtin_bit_cast(unsigned short, h);
}
__device__ __forceinline__ float h_bits2f(unsigned short s) {
    return (float)__builtin_bit_cast(_Float16, s);
}

// ---------------- kW: W -> fp16, transposed + padded: Wht[dir][col][k] ------
__global__ __launch_bounds__(256)
void kW_pack(const float* __restrict__ Wf, const float* __restrict__ Wb,
             _Float16* __restrict__ Wht)
{
    const int idx = blockIdx.x * 256 + threadIdx.x;   // < 2*1216*320
    const int dir = idx / (WCOLS * WK);
    const int rem = idx % (WCOLS * WK);
    const int col = rem / WK;
    const int k   = rem % WK;
    const float* __restrict__ W = dir ? Wb : Wf;
    float v = (col < G4 && k < HID) ? W[(size_t)k * G4 + col] : 0.f;
    Wht[idx] = (_Float16)v;
}

// ---------------- kU: pack U -> fp16 [dir][kq][cp] uint4, permuted cols -----
// packed col cp: slot = cp/600, w = cp%600, u = w>>1, p = w&1
//   -> orig col = slot*600 + p*300 + u
__global__ __launch_bounds__(256)
void kU_pack(const float* __restrict__ Uf, const float* __restrict__ Ub,
             uint4* __restrict__ Upk4f, uint4* __restrict__ Upk4b)
{
    const int idx = blockIdx.x * 256 + threadIdx.x;
    if (idx >= 2 * KQ * G4) return;
    const int dir = idx / (KQ * G4);
    const int rem = idx % (KQ * G4);
    const int kq  = rem / G4;
    const int cp  = rem % G4;
    const int slot = cp / 600;
    const int wwp  = cp % 600;
    const int col  = slot * 600 + (wwp & 1) * 300 + (wwp >> 1);
    const float* __restrict__ U = dir ? Ub : Uf;
    float v[8];
    #pragma unroll
    for (int u = 0; u < 8; ++u) {
        const int k = 8 * kq + u;
        v[u] = (k < HID) ? U[(size_t)k * G4 + col] : 0.f;
    }
    __half2 p0 = __floats2half2_rn(v[0], v[1]);
    __half2 p1 = __floats2half2_rn(v[2], v[3]);
    __half2 p2 = __floats2half2_rn(v[4], v[5]);
    __half2 p3 = __floats2half2_rn(v[6], v[7]);
    uint4 o;
    o.x = *(unsigned*)&p0; o.y = *(unsigned*)&p1;
    o.z = *(unsigned*)&p2; o.w = *(unsigned*)&p3;
    (dir ? Upk4b : Upk4f)[rem] = o;
}

// ---------------- k_init: out[r][c] = bfc[c] --------------------------------
__global__ __launch_bounds__(256)
void k_init(float* __restrict__ out, const float* __restrict__ bfc)
{
    const size_t i = (size_t)blockIdx.x * 256 + threadIdx.x;
    out[i] = bfc[i & 63];
}

// ---------------- K1: xg = emb[tokens] @ W + bias via MFMA fp16 -------------
// Output packed unit-major: orig col c -> pc = 4*(c%600%300) + 2*(c%600/300)
// + (c/600), i.e. unit u occupies halfs [4u,4u+4) as (i,cc,f,o).
__global__ __launch_bounds__(256)
void k1_xg(const int* __restrict__ tokens, const int* __restrict__ seqlen,
           const float* __restrict__ emb, const _Float16* __restrict__ Wht,
           const float* __restrict__ bf, const float* __restrict__ bb,
           __half* __restrict__ xgpf, __half* __restrict__ xgpb)
{
    const int z = blockIdx.z;
    const _Float16* __restrict__ Wh = Wht + (size_t)z * WCOLS * WK;
    const float* __restrict__ bias  = z ? bb : bf;
    __half* __restrict__ xgp        = z ? xgpb : xgpf;

    const int row0 = blockIdx.x * 64;
    const int b    = row0 >> 9;
    const int t0   = row0 & 511;
    if (t0 >= seqlen[b]) return;       // strip fully masked -> never consumed

    const int n0 = blockIdx.y * 64;

    __shared__ int toks[64];
    __shared__ __align__(16) _Float16 A_lds[64][40];
    __shared__ __align__(16) _Float16 B_lds[64][40];

    const int tid = threadIdx.x;
    if (tid < 64) toks[tid] = tokens[row0 + tid];
    __syncthreads();

    const int r = tid >> 2, q = tid & 3;     // staging identity
    const int lane = tid & 63, w = tid >> 6;
    const int lr = lane & 15, lk = lane >> 4;

    f32x4 acc[4];
    #pragma unroll
    for (int ct = 0; ct < 4; ++ct) acc[ct] = (f32x4){0.f, 0.f, 0.f, 0.f};

    const float* er = emb + (size_t)toks[r] * EMB;

    for (int kc = 0; kc < WK; kc += 32) {
        {
            half8 av;
            #pragma unroll
            for (int u = 0; u < 8; ++u) {
                const int k = kc + q * 8 + u;
                av[u] = (k < EMB) ? (_Float16)er[k] : (_Float16)0.f;
            }
            *(half8*)&A_lds[r][q * 8] = av;
        }
        *(half8*)&B_lds[r][q * 8] =
            *(const half8*)(Wh + (size_t)(n0 + r) * WK + kc + q * 8);
        __syncthreads();

        half8 af = *(const half8*)&A_lds[w * 16 + lr][lk * 8];
        #pragma unroll
        for (int ct = 0; ct < 4; ++ct) {
            half8 bf8 = *(const half8*)&B_lds[ct * 16 + lr][lk * 8];
            acc[ct] = __builtin_amdgcn_mfma_f32_16x16x32_f16(af, bf8,
                                                             acc[ct], 0, 0, 0);
        }
        __syncthreads();
    }

    #pragma unroll
    for (int ct = 0; ct < 4; ++ct) {
        const int col = n0 + ct * 16 + lr;
        if (col < G4) {
            const int rem  = col % 600;
            const int pc   = 4 * (rem % 300) + 2 * (rem / 300) + (col / 600);
            const float bv = bias[col];
            #pragma unroll
            for (int i = 0; i < 4; ++i) {
                const int row = row0 + w * 16 + lk * 4 + i;
                xgp[(size_t)row * G4 + pc] = __float2half(acc[ct][i] + bv);
            }
        }
    }
}

// ---------------- K2: LSTM scan, persistent-reg + LDS + streamed U ----------
// 128 blocks = 64 batches x 2 dirs, 704 threads, 157.2 KB dynamic LDS.
//   tid 0..599   : thread t owns packed cols t, t+600 (unit u=t>>1; even:
//                  i,cc dots; odd: f,o dots). U chunk-pairs per col: 16 held
//                  PERSISTENTLY in registers (read-only, loaded once), 16
//                  streamed (compiler-scheduled), 6 in LDS. Pair exchange
//                  via __shfl_xor(1); even thread runs the nonlinearity.
//   tid 640..703 : project prev step's h through fp16 W2s, atomicAdd into
//                  bfc-initialized out; overlapped with dot phase.
// ONE barrier per step. PR bisect: 12 clean (2318us) / 20 spilled (4989us).
__global__ __launch_bounds__(NTH, 3)
void k2_rnn(const int* __restrict__ seqlen,
            const uint4* __restrict__ Upk4f, const uint4* __restrict__ Upk4b,
            const __half* __restrict__ xgpf, const __half* __restrict__ xgpb,
            const float* __restrict__ Wfc, float* __restrict__ out)
{
    const int w   = blockIdx.x;
    const int dir = w & 1;
    const int b   = w >> 1;
    const int L   = seqlen[b];
    const uint4* __restrict__ Up   = dir ? Upk4b : Upk4f;
    const __half* __restrict__ xgp = dir ? xgpb  : xgpf;

    extern __shared__ __align__(16) char smem[];
    uint4*          Us   = (uint4*)smem;                       // [NC*1200]
    unsigned short* W2s  = (unsigned short*)(Us + NC * 1200);  // [300*64]
    float*          h32  = (float*)(W2s + 300 * 64);           // [2][304]
    unsigned short* h16  = (unsigned short*)(h32 + 2 * 304);   // [2][304]

    const int t = threadIdx.x;
    for (int i = t; i < NC * 1200; i += NTH) Us[i] = Up[i];
    for (int i = t; i < HID * TAGS; i += NTH)
        W2s[i] = f2h_bits(Wfc[(size_t)dir * HID * TAGS + i]);
    for (int i = t; i < 2 * 304; i += NTH) {
        h32[i] = 0.f;
        h16[i] = 0;
    }

    // persistent U slice: chunk-pairs kq = NC .. NC+PR-1, loaded ONCE
    uint4 P0[PR], P1[PR];
    if (t < 600) {
        const uint4* pp0 = Up + (size_t)NC * G4 + t;
        const uint4* pp1 = pp0 + 600;
        #pragma unroll
        for (int j = 0; j < PR; ++j) {
            P0[j] = pp0[(size_t)j * G4];
            P1[j] = pp1[(size_t)j * G4];
        }
    }
    __syncthreads();

    float c = 0.f;
    const int u    = t >> 1;      // unit (dot threads)
    const int pcol = t - 640;     // proj col if >= 0

    for (int ti = 0; ti < L; ++ti) {
        const int tf = dir ? (L - 1 - ti) : ti;
        const int rb = ti & 1;

        if (t < 600) {
            const unsigned xv =
                *(const unsigned*)(xgp + ((size_t)b * TT + tf) * G4 + 2 * t);
            float d0 = h_bits2f((unsigned short)(xv & 0xFFFF));
            float d1 = h_bits2f((unsigned short)(xv >> 16));
            const uint4* hq = (const uint4*)(h16 + rb * 304);

            // persistent chunks (kq = NC..NC+PR-1), zero memory traffic
            #pragma unroll
            for (int j = 0; j < PR; ++j) {
                const uint4 hh = hq[NC + j];
                d0 = fdot2f(P0[j].x, hh.x, d0);
                d0 = fdot2f(P0[j].y, hh.y, d0);
                d0 = fdot2f(P0[j].z, hh.z, d0);
                d0 = fdot2f(P0[j].w, hh.w, d0);
                d1 = fdot2f(P1[j].x, hh.x, d1);
                d1 = fdot2f(P1[j].y, hh.y, d1);
                d1 = fdot2f(P1[j].z, hh.z, d1);
                d1 = fdot2f(P1[j].w, hh.w, d1);
            }
            // streamed chunks (kq = NC+PR..37), compiler-scheduled
            const uint4* u0p = Up + (size_t)(NC + PR) * G4 + t;
            const uint4* u1p = u0p + 600;
            #pragma unroll
            for (int kq = 0; kq < NST; ++kq) {
                uint4 u0 = u0p[(size_t)kq * G4];
                uint4 u1 = u1p[(size_t)kq * G4];
                uint4 hh = hq[NC + PR + kq];
                d0 = fdot2f(u0.x, hh.x, d0);
                d0 = fdot2f(u0.y, hh.y, d0);
                d0 = fdot2f(u0.z, hh.z, d0);
                d0 = fdot2f(u0.w, hh.w, d0);
                d1 = fdot2f(u1.x, hh.x, d1);
                d1 = fdot2f(u1.y, hh.y, d1);
                d1 = fdot2f(u1.z, hh.z, d1);
                d1 = fdot2f(u1.w, hh.w, d1);
            }
            // LDS-cached chunks (kq = 0..NC-1)
            #pragma unroll
            for (int kq = 0; kq < NC; ++kq) {
                uint4 u0 = Us[kq * 1200 + t];
                uint4 u1 = Us[kq * 1200 + t + 600];
                uint4 hh = hq[kq];
                d0 = fdot2f(u0.x, hh.x, d0);
                d0 = fdot2f(u0.y, hh.y, d0);
                d0 = fdot2f(u0.z, hh.z, d0);
                d0 = fdot2f(u0.w, hh.w, d0);
                d1 = fdot2f(u1.x, hh.x, d1);
                d1 = fdot2f(u1.y, hh.y, d1);
                d1 = fdot2f(u1.z, hh.z, d1);
                d1 = fdot2f(u1.w, hh.w, d1);
            }
            // pair exchange: even thread (i,cc) gets odd's (f,o)
            const float fd0 = __shfl_xor(d0, 1);
            const float fd1 = __shfl_xor(d1, 1);
            if (!(t & 1)) {
                const float i_ = sigm(d0);
                const float z_ = tanh_fast(d1);
                const float f_ = sigm(fd0);
                const float o_ = sigm(fd1);
                c = fmaf(f_, c, i_ * z_);
                const float hn = o_ * tanh_fast(c);
                h32[(rb ^ 1) * 304 + u] = hn;
                h16[(rb ^ 1) * 304 + u] = f2h_bits(hn);
            }
        } else if (pcol >= 0 && ti > 0) {
            // project h of previous step (buffer rb), overlapped with dots
            const float* hs = h32 + rb * 304;
            float acc = 0.f;
            for (int j2 = 0; j2 < HID; j2 += 4) {
                f32x4 h4 = *(const f32x4*)&hs[j2];
                acc = fmaf(h4.x, h_bits2f(W2s[(j2 + 0) * 64 + pcol]), acc);
                acc = fmaf(h4.y, h_bits2f(W2s[(j2 + 1) * 64 + pcol]), acc);
                acc = fmaf(h4.z, h_bits2f(W2s[(j2 + 2) * 64 + pcol]), acc);
                acc = fmaf(h4.w, h_bits2f(W2s[(j2 + 3) * 64 + pcol]), acc);
            }
            const int rowp = dir ? (tf + 1) : (tf - 1);
            atomicAdd(out + ((size_t)b * TT + rowp) * TAGS + pcol, acc);
        }
        __syncthreads();   // the ONE barrier: h(ti) published for step ti+1
    }

    // final projection (h of step L-1 is in buffer L&1) + tail fill
    if (pcol >= 0) {
        const float* hs = h32 + (L & 1) * 304;
        float acc = 0.f;
        for (int j2 = 0; j2 < HID; j2 += 4) {
            f32x4 h4 = *(const f32x4*)&hs[j2];
            acc = fmaf(h4.x, h_bits2f(W2s[(j2 + 0) * 64 + pcol]), acc);
            acc = fmaf(h4.y, h_bits2f(W2s[(j2 + 1) * 64 + pcol]), acc);
            acc = fmaf(h4.z, h_bits2f(W2s[(j2 + 2) * 64 + pcol]), acc);
            acc = fmaf(h4.w, h_bits2f(W2s[(j2 + 3) * 64 + pcol]), acc);
        }
        if (dir == 0) {
            float* o = out + (size_t)b * TT * TAGS + pcol;
            for (int tt = L - 1; tt < TT; ++tt)
                atomicAdd(o + (size_t)tt * TAGS, acc);
        } else {
            atomicAdd(out + (size_t)b * TT * TAGS + pcol, acc);
        }
    }
}

extern "C" void kernel_launch(void* const* d_in, const int* in_sizes, int n_in,
                              void* d_out, int out_size, void* d_ws, size_t ws_size,
                              hipStream_t stream)
{
    const int*   tokens = (const int*)d_in[0];
    const int*   seqlen = (const int*)d_in[1];
    const float* emb    = (const float*)d_in[2];
    const float* Wf     = (const float*)d_in[3];
    const float* Uf     = (const float*)d_in[4];
    const float* bf     = (const float*)d_in[5];
    const float* Wb     = (const float*)d_in[6];
    const float* Ub     = (const float*)d_in[7];
    const float* bb     = (const float*)d_in[8];
    const float* Wfc    = (const float*)d_in[9];
    const float* bfc    = (const float*)d_in[10];
    float* out = (float*)d_out;

    // ws: xgpf | xgpb (fp16, packed) | Upk4f | Upk4b | Wht
    const size_t xg_elems = (size_t)MM * G4;
    const size_t up_elems = (size_t)KQ * G4;            // uint4 per dir
    const size_t wh_elems = (size_t)2 * WCOLS * WK;     // fp16
    const size_t need = xg_elems * 2 * sizeof(__half)
                      + 2 * up_elems * sizeof(uint4)
                      + wh_elems * sizeof(_Float16);
    if (ws_size < need) {
        hipMemsetAsync(d_out, 0, (size_t)out_size * sizeof(float), stream);
        return;
    }
    __half*   xgpf  = (__half*)d_ws;
    __half*   xgpb  = xgpf + xg_elems;
    uint4*    Upk4f = (uint4*)(xgpb + xg_elems);
    uint4*    Upk4b = Upk4f + up_elems;
    _Float16* Wht   = (_Float16*)(Upk4b + up_elems);

    hipLaunchKernelGGL(kU_pack, dim3((2 * KQ * G4 + 255) / 256), dim3(256),
                       0, stream, Uf, Ub, Upk4f, Upk4b);
    hipLaunchKernelGGL(kW_pack, dim3((int)(wh_elems / 256)), dim3(256),
                       0, stream, Wf, Wb, Wht);
    hipLaunchKernelGGL(k_init, dim3(MM * TAGS / 256), dim3(256), 0, stream,
                       out, bfc);
    dim3 g1(MM / 64, (G4 + 63) / 64, 2);
    hipLaunchKernelGGL(k1_xg, g1, dim3(256), 0, stream,
                       tokens, seqlen, emb, Wht, bf, bb, xgpf, xgpb);

    hipFuncSetAttribute((const void*)k2_rnn,
                        hipFuncAttributeMaxDynamicSharedMemorySize, SMEM2);
    hipLaunchKernelGGL(k2_rnn, dim3(2 * BB), dim3(NTH), SMEM2, stream,
                       seqlen, Upk4f, Upk4b, xgpf, xgpb, Wfc, out);
}

// Round 15
// 2557.245 us; speedup vs baseline: 2.0530x; 2.0530x over previous
//
#include <hip/hip_runtime.h>
#include <hip/hip_fp16.h>

typedef float f32x4 __attribute__((ext_vector_type(4)));
typedef _Float16 half8 __attribute__((ext_vector_type(8)));
typedef _Float16 h2_t __attribute__((ext_vector_type(2)));

#define EMB   300
#define HID   300
#define G4    1200
#define TAGS  64
#define BB    64
#define TT    512
#define MM    (BB*TT)
#define KQ    38        // uint4 (8 fp16) k-chunks: 304 k (300 + 4 pad)
#define NC    6         // k-chunks of U cached in LDS
#define PR    12        // k-chunks of U persistent in registers (96 regs)
#define NST   (KQ - NC - PR)   // 20 streamed chunks
#define NTH   704
#define WCOLS 1216      // padded col count of Wht
#define WK    320       // padded k of Wht
// k2 dynamic LDS: Us | W2s | h32 | h16
#define SMEM2 (NC*1200*16 + 300*64*2 + 2*304*4 + 2*304*2)

__device__ __forceinline__ float sigm(float x) {
    return 1.0f / (1.0f + __expf(-x));
}
__device__ __forceinline__ float tanh_fast(float x) {
    float e = __expf(-2.0f * fabsf(x));
    float r = (1.0f - e) / (1.0f + e);
    return copysignf(r, x);
}
__device__ __forceinline__ float fdot2f(unsigned u, unsigned h, float acc) {
#if __has_builtin(__builtin_amdgcn_fdot2)
    return __builtin_amdgcn_fdot2(__builtin_bit_cast(h2_t, u),
                                  __builtin_bit_cast(h2_t, h), acc, false);
#else
    h2_t a = __builtin_bit_cast(h2_t, u), b = __builtin_bit_cast(h2_t, h);
    acc = fmaf((float)a.x, (float)b.x, acc);
    return fmaf((float)a.y, (float)b.y, acc);
#endif
}
__device__ __forceinline__ unsigned short f2h_bits(float f) {
    _Float16 h = (_Float16)f;
    return __builtin_bit_cast(unsigned short, h);
}
__device__ __forceinline__ float h_bits2f(unsigned short s) {
    return (float)__builtin_bit_cast(_Float16, s);
}

// ---------------- kW: W -> fp16, transposed + padded: Wht[dir][col][k] ------
__global__ __launch_bounds__(256)
void kW_pack(const float* __restrict__ Wf, const float* __restrict__ Wb,
             _Float16* __restrict__ Wht)
{
    const int idx = blockIdx.x * 256 + threadIdx.x;   // < 2*1216*320
    const int dir = idx / (WCOLS * WK);
    const int rem = idx % (WCOLS * WK);
    const int col = rem / WK;
    const int k   = rem % WK;
    const float* __restrict__ W = dir ? Wb : Wf;
    float v = (col < G4 && k < HID) ? W[(size_t)k * G4 + col] : 0.f;
    Wht[idx] = (_Float16)v;
}

// ---------------- kU: pack U -> fp16 [dir][kq][cp] uint4, permuted cols -----
// packed col cp: slot = cp/600, w = cp%600, u = w>>1, p = w&1
//   -> orig col = slot*600 + p*300 + u
__global__ __launch_bounds__(256)
void kU_pack(const float* __restrict__ Uf, const float* __restrict__ Ub,
             uint4* __restrict__ Upk4f, uint4* __restrict__ Upk4b)
{
    const int idx = blockIdx.x * 256 + threadIdx.x;
    if (idx >= 2 * KQ * G4) return;
    const int dir = idx / (KQ * G4);
    const int rem = idx % (KQ * G4);
    const int kq  = rem / G4;
    const int cp  = rem % G4;
    const int slot = cp / 600;
    const int wwp  = cp % 600;
    const int col  = slot * 600 + (wwp & 1) * 300 + (wwp >> 1);
    const float* __restrict__ U = dir ? Ub : Uf;
    float v[8];
    #pragma unroll
    for (int u = 0; u < 8; ++u) {
        const int k = 8 * kq + u;
        v[u] = (k < HID) ? U[(size_t)k * G4 + col] : 0.f;
    }
    __half2 p0 = __floats2half2_rn(v[0], v[1]);
    __half2 p1 = __floats2half2_rn(v[2], v[3]);
    __half2 p2 = __floats2half2_rn(v[4], v[5]);
    __half2 p3 = __floats2half2_rn(v[6], v[7]);
    uint4 o;
    o.x = *(unsigned*)&p0; o.y = *(unsigned*)&p1;
    o.z = *(unsigned*)&p2; o.w = *(unsigned*)&p3;
    (dir ? Upk4b : Upk4f)[rem] = o;
}

// ---------------- k_init: out[r][c] = bfc[c] --------------------------------
__global__ __launch_bounds__(256)
void k_init(float* __restrict__ out, const float* __restrict__ bfc)
{
    const size_t i = (size_t)blockIdx.x * 256 + threadIdx.x;
    out[i] = bfc[i & 63];
}

// ---------------- K1: xg = emb[tokens] @ W + bias via MFMA fp16 -------------
// Output packed unit-major: orig col c -> pc = 4*(c%600%300) + 2*(c%600/300)
// + (c/600), i.e. unit u occupies halfs [4u,4u+4) as (i,cc,f,o).
__global__ __launch_bounds__(256)
void k1_xg(const int* __restrict__ tokens, const int* __restrict__ seqlen,
           const float* __restrict__ emb, const _Float16* __restrict__ Wht,
           const float* __restrict__ bf, const float* __restrict__ bb,
           __half* __restrict__ xgpf, __half* __restrict__ xgpb)
{
    const int z = blockIdx.z;
    const _Float16* __restrict__ Wh = Wht + (size_t)z * WCOLS * WK;
    const float* __restrict__ bias  = z ? bb : bf;
    __half* __restrict__ xgp        = z ? xgpb : xgpf;

    const int row0 = blockIdx.x * 64;
    const int b    = row0 >> 9;
    const int t0   = row0 & 511;
    if (t0 >= seqlen[b]) return;       // strip fully masked -> never consumed

    const int n0 = blockIdx.y * 64;

    __shared__ int toks[64];
    __shared__ __align__(16) _Float16 A_lds[64][40];
    __shared__ __align__(16) _Float16 B_lds[64][40];

    const int tid = threadIdx.x;
    if (tid < 64) toks[tid] = tokens[row0 + tid];
    __syncthreads();

    const int r = tid >> 2, q = tid & 3;     // staging identity
    const int lane = tid & 63, w = tid >> 6;
    const int lr = lane & 15, lk = lane >> 4;

    f32x4 acc[4];
    #pragma unroll
    for (int ct = 0; ct < 4; ++ct) acc[ct] = (f32x4){0.f, 0.f, 0.f, 0.f};

    const float* er = emb + (size_t)toks[r] * EMB;

    for (int kc = 0; kc < WK; kc += 32) {
        {
            half8 av;
            #pragma unroll
            for (int u = 0; u < 8; ++u) {
                const int k = kc + q * 8 + u;
                av[u] = (k < EMB) ? (_Float16)er[k] : (_Float16)0.f;
            }
            *(half8*)&A_lds[r][q * 8] = av;
        }
        *(half8*)&B_lds[r][q * 8] =
            *(const half8*)(Wh + (size_t)(n0 + r) * WK + kc + q * 8);
        __syncthreads();

        half8 af = *(const half8*)&A_lds[w * 16 + lr][lk * 8];
        #pragma unroll
        for (int ct = 0; ct < 4; ++ct) {
            half8 bf8 = *(const half8*)&B_lds[ct * 16 + lr][lk * 8];
            acc[ct] = __builtin_amdgcn_mfma_f32_16x16x32_f16(af, bf8,
                                                             acc[ct], 0, 0, 0);
        }
        __syncthreads();
    }

    #pragma unroll
    for (int ct = 0; ct < 4; ++ct) {
        const int col = n0 + ct * 16 + lr;
        if (col < G4) {
            const int rem  = col % 600;
            const int pc   = 4 * (rem % 300) + 2 * (rem / 300) + (col / 600);
            const float bv = bias[col];
            #pragma unroll
            for (int i = 0; i < 4; ++i) {
                const int row = row0 + w * 16 + lk * 4 + i;
                xgp[(size_t)row * G4 + pc] = __float2half(acc[ct][i] + bv);
            }
        }
    }
}

// ---------------- K2: LSTM scan, persistent-reg + LDS + streamed U ----------
// 128 blocks = 64 batches x 2 dirs, 704 threads, 157.2 KB dynamic LDS.
//   tid 0..599   : thread t owns packed cols t, t+600 (unit u=t>>1; even:
//                  i,cc dots; odd: f,o dots). U chunk-pairs per col: 12 held
//                  PERSISTENTLY in registers (read-only, loaded once), 20
//                  streamed (compiler-scheduled), 6 in LDS. Pair exchange
//                  via __shfl_xor(1); even thread runs the nonlinearity.
//   tid 640..703 : project prev step's h through fp16 W2s, atomicAdd into
//                  bfc-initialized out; overlapped with dot phase.
// ONE barrier per step. PR sweep: 8=2515, 12=2318 (best), 16/20 spill.
__global__ __launch_bounds__(NTH, 3)
void k2_rnn(const int* __restrict__ seqlen,
            const uint4* __restrict__ Upk4f, const uint4* __restrict__ Upk4b,
            const __half* __restrict__ xgpf, const __half* __restrict__ xgpb,
            const float* __restrict__ Wfc, float* __restrict__ out)
{
    const int w   = blockIdx.x;
    const int dir = w & 1;
    const int b   = w >> 1;
    const int L   = seqlen[b];
    const uint4* __restrict__ Up   = dir ? Upk4b : Upk4f;
    const __half* __restrict__ xgp = dir ? xgpb  : xgpf;

    extern __shared__ __align__(16) char smem[];
    uint4*          Us   = (uint4*)smem;                       // [NC*1200]
    unsigned short* W2s  = (unsigned short*)(Us + NC * 1200);  // [300*64]
    float*          h32  = (float*)(W2s + 300 * 64);           // [2][304]
    unsigned short* h16  = (unsigned short*)(h32 + 2 * 304);   // [2][304]

    const int t = threadIdx.x;
    for (int i = t; i < NC * 1200; i += NTH) Us[i] = Up[i];
    for (int i = t; i < HID * TAGS; i += NTH)
        W2s[i] = f2h_bits(Wfc[(size_t)dir * HID * TAGS + i]);
    for (int i = t; i < 2 * 304; i += NTH) {
        h32[i] = 0.f;
        h16[i] = 0;
    }

    // persistent U slice: chunk-pairs kq = NC .. NC+PR-1, loaded ONCE
    uint4 P0[PR], P1[PR];
    if (t < 600) {
        const uint4* pp0 = Up + (size_t)NC * G4 + t;
        const uint4* pp1 = pp0 + 600;
        #pragma unroll
        for (int j = 0; j < PR; ++j) {
            P0[j] = pp0[(size_t)j * G4];
            P1[j] = pp1[(size_t)j * G4];
        }
    }
    __syncthreads();

    float c = 0.f;
    const int u    = t >> 1;      // unit (dot threads)
    const int pcol = t - 640;     // proj col if >= 0

    for (int ti = 0; ti < L; ++ti) {
        const int tf = dir ? (L - 1 - ti) : ti;
        const int rb = ti & 1;

        if (t < 600) {
            const unsigned xv =
                *(const unsigned*)(xgp + ((size_t)b * TT + tf) * G4 + 2 * t);
            float d0 = h_bits2f((unsigned short)(xv & 0xFFFF));
            float d1 = h_bits2f((unsigned short)(xv >> 16));
            const uint4* hq = (const uint4*)(h16 + rb * 304);

            // persistent chunks (kq = NC..NC+PR-1), zero memory traffic
            #pragma unroll
            for (int j = 0; j < PR; ++j) {
                const uint4 hh = hq[NC + j];
                d0 = fdot2f(P0[j].x, hh.x, d0);
                d0 = fdot2f(P0[j].y, hh.y, d0);
                d0 = fdot2f(P0[j].z, hh.z, d0);
                d0 = fdot2f(P0[j].w, hh.w, d0);
                d1 = fdot2f(P1[j].x, hh.x, d1);
                d1 = fdot2f(P1[j].y, hh.y, d1);
                d1 = fdot2f(P1[j].z, hh.z, d1);
                d1 = fdot2f(P1[j].w, hh.w, d1);
            }
            // streamed chunks (kq = NC+PR..37), compiler-scheduled
            const uint4* u0p = Up + (size_t)(NC + PR) * G4 + t;
            const uint4* u1p = u0p + 600;
            #pragma unroll 8
            for (int kq = 0; kq < NST; ++kq) {
                uint4 u0 = u0p[(size_t)kq * G4];
                uint4 u1 = u1p[(size_t)kq * G4];
                uint4 hh = hq[NC + PR + kq];
                d0 = fdot2f(u0.x, hh.x, d0);
                d0 = fdot2f(u0.y, hh.y, d0);
                d0 = fdot2f(u0.z, hh.z, d0);
                d0 = fdot2f(u0.w, hh.w, d0);
                d1 = fdot2f(u1.x, hh.x, d1);
                d1 = fdot2f(u1.y, hh.y, d1);
                d1 = fdot2f(u1.z, hh.z, d1);
                d1 = fdot2f(u1.w, hh.w, d1);
            }
            // LDS-cached chunks (kq = 0..NC-1)
            #pragma unroll
            for (int kq = 0; kq < NC; ++kq) {
                uint4 u0 = Us[kq * 1200 + t];
                uint4 u1 = Us[kq * 1200 + t + 600];
                uint4 hh = hq[kq];
                d0 = fdot2f(u0.x, hh.x, d0);
                d0 = fdot2f(u0.y, hh.y, d0);
                d0 = fdot2f(u0.z, hh.z, d0);
                d0 = fdot2f(u0.w, hh.w, d0);
                d1 = fdot2f(u1.x, hh.x, d1);
                d1 = fdot2f(u1.y, hh.y, d1);
                d1 = fdot2f(u1.z, hh.z, d1);
                d1 = fdot2f(u1.w, hh.w, d1);
            }
            // pair exchange: even thread (i,cc) gets odd's (f,o)
            const float fd0 = __shfl_xor(d0, 1);
            const float fd1 = __shfl_xor(d1, 1);
            if (!(t & 1)) {
                const float i_ = sigm(d0);
                const float z_ = tanh_fast(d1);
                const float f_ = sigm(fd0);
                const float o_ = sigm(fd1);
                c = fmaf(f_, c, i_ * z_);
                const float hn = o_ * tanh_fast(c);
                h32[(rb ^ 1) * 304 + u] = hn;
                h16[(rb ^ 1) * 304 + u] = f2h_bits(hn);
            }
        } else if (pcol >= 0 && ti > 0) {
            // project h of previous step (buffer rb), overlapped with dots
            const float* hs = h32 + rb * 304;
            float acc = 0.f;
            for (int j2 = 0; j2 < HID; j2 += 4) {
                f32x4 h4 = *(const f32x4*)&hs[j2];
                acc = fmaf(h4.x, h_bits2f(W2s[(j2 + 0) * 64 + pcol]), acc);
                acc = fmaf(h4.y, h_bits2f(W2s[(j2 + 1) * 64 + pcol]), acc);
                acc = fmaf(h4.z, h_bits2f(W2s[(j2 + 2) * 64 + pcol]), acc);
                acc = fmaf(h4.w, h_bits2f(W2s[(j2 + 3) * 64 + pcol]), acc);
            }
            const int rowp = dir ? (tf + 1) : (tf - 1);
            atomicAdd(out + ((size_t)b * TT + rowp) * TAGS + pcol, acc);
        }
        __syncthreads();   // the ONE barrier: h(ti) published for step ti+1
    }

    // final projection (h of step L-1 is in buffer L&1) + tail fill
    if (pcol >= 0) {
        const float* hs = h32 + (L & 1) * 304;
        float acc = 0.f;
        for (int j2 = 0; j2 < HID; j2 += 4) {
            f32x4 h4 = *(const f32x4*)&hs[j2];
            acc = fmaf(h4.x, h_bits2f(W2s[(j2 + 0) * 64 + pcol]), acc);
            acc = fmaf(h4.y, h_bits2f(W2s[(j2 + 1) * 64 + pcol]), acc);
            acc = fmaf(h4.z, h_bits2f(W2s[(j2 + 2) * 64 + pcol]), acc);
            acc = fmaf(h4.w, h_bits2f(W2s[(j2 + 3) * 64 + pcol]), acc);
        }
        if (dir == 0) {
            float* o = out + (size_t)b * TT * TAGS + pcol;
            for (int tt = L - 1; tt < TT; ++tt)
                atomicAdd(o + (size_t)tt * TAGS, acc);
        } else {
            atomicAdd(out + (size_t)b * TT * TAGS + pcol, acc);
        }
    }
}

extern "C" void kernel_launch(void* const* d_in, const int* in_sizes, int n_in,
                              void* d_out, int out_size, void* d_ws, size_t ws_size,
                              hipStream_t stream)
{
    const int*   tokens = (const int*)d_in[0];
    const int*   seqlen = (const int*)d_in[1];
    const float* emb    = (const float*)d_in[2];
    const float* Wf     = (const float*)d_in[3];
    const float* Uf     = (const float*)d_in[4];
    const float* bf     = (const float*)d_in[5];
    const float* Wb     = (const float*)d_in[6];
    const float* Ub     = (const float*)d_in[7];
    const float* bb     = (const float*)d_in[8];
    const float* Wfc    = (const float*)d_in[9];
    const float* bfc    = (const float*)d_in[10];
    float* out = (float*)d_out;

    // ws: xgpf | xgpb (fp16, packed) | Upk4f | Upk4b | Wht
    const size_t xg_elems = (size_t)MM * G4;
    const size_t up_elems = (size_t)KQ * G4;            // uint4 per dir
    const size_t wh_elems = (size_t)2 * WCOLS * WK;     // fp16
    const size_t need = xg_elems * 2 * sizeof(__half)
                      + 2 * up_elems * sizeof(uint4)
                      + wh_elems * sizeof(_Float16);
    if (ws_size < need) {
        hipMemsetAsync(d_out, 0, (size_t)out_size * sizeof(float), stream);
        return;
    }
    __half*   xgpf  = (__half*)d_ws;
    __half*   xgpb  = xgpf + xg_elems;
    uint4*    Upk4f = (uint4*)(xgpb + xg_elems);
    uint4*    Upk4b = Upk4f + up_elems;
    _Float16* Wht   = (_Float16*)(Upk4b + up_elems);

    hipLaunchKernelGGL(kU_pack, dim3((2 * KQ * G4 + 255) / 256), dim3(256),
                       0, stream, Uf, Ub, Upk4f, Upk4b);
    hipLaunchKernelGGL(kW_pack, dim3((int)(wh_elems / 256)), dim3(256),
                       0, stream, Wf, Wb, Wht);
    hipLaunchKernelGGL(k_init, dim3(MM * TAGS / 256), dim3(256), 0, stream,
                       out, bfc);
    dim3 g1(MM / 64, (G4 + 63) / 64, 2);
    hipLaunchKernelGGL(k1_xg, g1, dim3(256), 0, stream,
                       tokens, seqlen, emb, Wht, bf, bb, xgpf, xgpb);

    hipFuncSetAttribute((const void*)k2_rnn,
                        hipFuncAttributeMaxDynamicSharedMemorySize, SMEM2);
    hipLaunchKernelGGL(k2_rnn, dim3(2 * BB), dim3(NTH), SMEM2, stream,
                       seqlen, Upk4f, Upk4b, xgpf, xgpb, Wfc, out);
}